// Round 16
// baseline (175.920 us; speedup 1.0000x reference)
//
#include <hip/hip_runtime.h>
#include <hip/hip_bf16.h>
#include <math.h>

typedef __attribute__((ext_vector_type(8))) short short8v;
typedef __attribute__((ext_vector_type(4))) float float4v;

// ---------------- workspace layout (dword offsets) ----------------
static const size_t F_RAWP1B = 0;              // bf16 ch-last pooled raw conv1 [8192][144][12dw] = 14,155,776
static const size_t F_C2P    = 14155776;       // fp32 pooled raw conv2 [8192][800] = 6,553,600
static const size_t F_PART1  = 20709376;       // [40][2048] = 81,920
static const size_t F_PART2  = 20791296;       // [100][4096] = 409,600
static const size_t F_PART3  = 21200896;       // 256*20 = 5,120
static const size_t F_BN1    = 21206016;       // 40
static const size_t F_BN2    = 21206056;       // 100
static const size_t F_SRAW   = 21206156;       // 2560
static const size_t F_WB2    = 21208716;       // 19456 (76*64*8 bf16)
static const size_t F_WB1    = 21228172;       // 512   (32*32 bf16)
static const size_t F_SPART  = 21228684;       // 256*2560 = 655,360
// overlays in rawp1b region (dead after conv2):
static const size_t F_HRAW   = 0;              // 8192*10
static const size_t F_MU     = 81920;          // 8192*256

__device__ __forceinline__ float relu_(float v) { return v > 0.f ? v : 0.f; }

__device__ __forceinline__ unsigned int pack_bf16x2(float a, float b) {
  __hip_bfloat16 ha = __float2bfloat16(a), hb = __float2bfloat16(b);
  unsigned short ua, ub;
  __builtin_memcpy(&ua, &ha, 2); __builtin_memcpy(&ub, &hb, 2);
  return ((unsigned int)ub << 16) | ua;
}

__device__ __forceinline__ unsigned short cvt_bf16(float a) {
  __hip_bfloat16 h = __float2bfloat16(a);
  unsigned short u; __builtin_memcpy(&u, &h, 2);
  return u;
}

__device__ __forceinline__ float pick_(float a, float b, bool mx) {
  return mx ? fmaxf(a, b) : fminf(a, b);
}

// ---- merged weight prep: wb1[n(32)][k(32)] (k=kh*6+kw) + wb2[cc(76)][n(64)][j(8)] ----
__global__ __launch_bounds__(256) void k_wprep(
    const float* __restrict__ w1, const float* __restrict__ w2,
    unsigned short* __restrict__ wb1, unsigned short* __restrict__ wb2)
{
  const int gi = blockIdx.x * 256 + threadIdx.x;     // 39936 total
  if (gi < 1024) {
    const int n = gi >> 5, k = gi & 31;
    const int kh = k / 6, kw = k - kh*6;
    float v = (n < 20 && kh < 5 && kw < 5) ? w1[n*25 + kh*5 + kw] : 0.f;
    wb1[gi] = cvt_bf16(v);
  } else {
    const int idx = gi - 1024;                       // 38912
    const int cc = idx >> 9;
    const int rem = idx & 511;
    const int n = rem >> 3, j = rem & 7;
    float v = 0.f;
    if (cc < 75 && n < 50) {
      const int khw = cc / 3, icg = cc - khw*3;
      const int ic = icg*8 + j;
      if (ic < 20) {
        const int kh = khw / 5, kw = khw - kh*5;
        v = w2[((n*20 + ic)*5 + kh)*5 + kw];
      }
    }
    wb2[idx] = cvt_bf16(v);
  }
}

// ---- conv1 MFMA implicit GEMM (R15-measured v3), part1 transposed write ----
__global__ __launch_bounds__(256) void k_conv1_mfma(
    const float* __restrict__ x, const unsigned short* __restrict__ wb1,
    const float* __restrict__ g1, unsigned int* __restrict__ rawp1b,
    float* __restrict__ part)
{
  __shared__ alignas(16) unsigned short xpk[2][1568];   // [buf][2 copies][28][28]
  __shared__ float sred[4][32], qred[4][32];
  const int tid = threadIdx.x, blk = blockIdx.x;
  const int img0 = blk * 4;
  const int wave = tid >> 6, lane = tid & 63, lo = lane & 15, hi = lane >> 4;

  // ---- hoisted per-block setup ----
  const short8v bfr0 = *(const short8v*)(wb1 + (lo*32 + hi*8));
  const short8v bfr1 = *(const short8v*)(wb1 + ((16+lo)*32 + hi*8));
  const unsigned enc = (hi==0) ? 0x0E020100u
                     : (hi==1) ? 0x1D1C100Fu
                     : (hi==2) ? 0x2C2B2A1Eu
                     :           0x003A3938u;   // hi=3: jj3 = zero-weight dummy
  const int off0 = enc & 255, off1 = (enc>>8)&255, off2 = (enc>>16)&255, off3 = enc>>24;
  const int pb   = (lo & 1) * 392;              // parity copy, dwords
  const int oyp  = (lo >> 1) & 1, qoff = lo >> 2;
  const int inv  = pb + (6*wave + oyp)*14;
  const bool gp0 = (g1[lo] >= 0.f);
  const bool gp1 = (lo < 4) ? (g1[16+lo] >= 0.f) : true;
  // staging geometry: 224 active threads, 8-per-row (7 quads + 1 idle)
  const int sr = tid >> 3, sq = tid & 7;
  const bool act = (tid < 224) && (sq < 7);
  const int su0 = sr*7 + sq;                    // uint2 index, copy0
  const int su1 = 196 + su0;                    // uint2 index, copy1

  float4 sv = make_float4(0.f, 0.f, 0.f, 0.f);
  // prologue: stage image 0
  if (act) sv = *(const float4*)(x + (size_t)img0 * 784 + sr*28 + 4*sq);
  {
    float n0 = __shfl_down(sv.x, 1);
    n0 = (sq == 6) ? 0.f : n0;
    if (act) {
      uint2* xb2 = (uint2*)&xpk[0][0];
      uint2 t0; t0.x = pack_bf16x2(sv.x, sv.y); t0.y = pack_bf16x2(sv.z, sv.w);
      uint2 t1; t1.x = pack_bf16x2(sv.y, sv.z); t1.y = pack_bf16x2(sv.w, n0);
      xb2[su0] = t0;
      xb2[su1] = t1;
    }
  }
  __syncthreads();

  // block-level stats, per-t3 accumulators (static indexing)
  float bs0[3] = {0.f, 0.f, 0.f}, bq0[3] = {0.f, 0.f, 0.f};
  float bs1[3] = {0.f, 0.f, 0.f}, bq1[3] = {0.f, 0.f, 0.f};
  int cur = 0;
  for (int ii = 0; ii < 4; ++ii) {
    // issue next image's global load early (latency hides under compute)
    if (ii < 3 && act)
      sv = *(const float4*)(x + (size_t)(img0 + ii + 1) * 784 + sr*28 + 4*sq);
    const unsigned int* xpd = (const unsigned int*)&xpk[cur][0];
    unsigned int* dst = rawp1b + (size_t)(img0 + ii) * 1728;

    #pragma unroll 1
    for (int g = 0; g < 3; ++g) {
      float4v acc[3][2];
      #pragma unroll
      for (int t3 = 0; t3 < 3; ++t3) {
        acc[t3][0] = (float4v){0.f,0.f,0.f,0.f};
        acc[t3][1] = (float4v){0.f,0.f,0.f,0.f};
      }
      #pragma unroll
      for (int t3 = 0; t3 < 3; ++t3) {
        const int base = inv + g*28 + t3*4 + qoff;
        union { unsigned int u[4]; short8v v; } cu;
        cu.u[0] = xpd[base + off0];
        cu.u[1] = xpd[base + off1];
        cu.u[2] = xpd[base + off2];
        cu.u[3] = xpd[base + off3];
        acc[t3][0] = __builtin_amdgcn_mfma_f32_16x16x32_bf16(cu.v, bfr0, acc[t3][0], 0, 0, 0);
        acc[t3][1] = __builtin_amdgcn_mfma_f32_16x16x32_bf16(cu.v, bfr1, acc[t3][1], 0, 0, 0);
      }
      #pragma unroll
      for (int t3 = 0; t3 < 3; ++t3) {
        const int T = wave*9 + g*3 + t3;
        const int q = T*4 + hi;
        const float4v v0 = acc[t3][0];
        const float4v v1 = acc[t3][1];
        #pragma unroll
        for (int r = 0; r < 4; ++r) { bs0[t3] += v0[r]; bq0[t3] += v0[r]*v0[r]; }
        #pragma unroll
        for (int r = 0; r < 4; ++r) { bs1[t3] += v1[r]; bq1[t3] += v1[r]*v1[r]; }
        const float p0 = pick_(pick_(v0[0], v0[1], gp0), pick_(v0[2], v0[3], gp0), gp0);
        const float p1 = pick_(pick_(v1[0], v1[1], gp1), pick_(v1[2], v1[3], gp1), gp1);
        const float o0 = __shfl_down(p0, 1);
        const float o1 = __shfl_down(p1, 1);
        if ((lo & 1) == 0) {
          dst[q*12 + (lo >> 1)] = pack_bf16x2(p0, o0);          // oc pair (lo, lo+1)
          if (lo < 8)
            dst[q*12 + 8 + (lo >> 1)] = pack_bf16x2(p1, o1);    // oc 16.. (pads=0)
        }
      }
    }

    // write next image into the other buffer (disjoint from xpk[cur])
    if (ii < 3) {
      float n0 = __shfl_down(sv.x, 1);
      n0 = (sq == 6) ? 0.f : n0;
      if (act) {
        uint2* xb2 = (uint2*)&xpk[cur ^ 1][0];
        uint2 t0; t0.x = pack_bf16x2(sv.x, sv.y); t0.y = pack_bf16x2(sv.z, sv.w);
        uint2 t1; t1.x = pack_bf16x2(sv.y, sv.z); t1.y = pack_bf16x2(sv.w, n0);
        xb2[su0] = t0;
        xb2[su1] = t1;
      }
    }
    __syncthreads();
    cur ^= 1;
  }

  // ---- single block-level stats reduction ----
  float bsv0 = bs0[0] + bs0[1] + bs0[2], bqv0 = bq0[0] + bq0[1] + bq0[2];
  float bsv1 = bs1[0] + bs1[1] + bs1[2], bqv1 = bq1[0] + bq1[1] + bq1[2];
  bsv0 += __shfl_down(bsv0, 32); bqv0 += __shfl_down(bqv0, 32);
  bsv0 += __shfl_down(bsv0, 16); bqv0 += __shfl_down(bqv0, 16);
  bsv1 += __shfl_down(bsv1, 32); bqv1 += __shfl_down(bqv1, 32);
  bsv1 += __shfl_down(bsv1, 16); bqv1 += __shfl_down(bqv1, 16);
  if (hi == 0) {
    sred[wave][lo] = bsv0; sred[wave][16+lo] = bsv1;
    qred[wave][lo] = bqv0; qred[wave][16+lo] = bqv1;
  }
  __syncthreads();
  if (tid < 20) {
    float s = 0.f, q = 0.f;
    #pragma unroll
    for (int w2 = 0; w2 < 4; ++w2) { s += sred[w2][tid]; q += qred[w2][tid]; }
    part[(size_t)tid*2048 + blk]        = s;    // transposed [40][2048]
    part[(size_t)(20 + tid)*2048 + blk] = q;
  }
}

// ---- conv2 implicit-GEMM MFMA: 128 threads, 2 imgs/block, grid 4096 ----
// Same per-image layout (6912 B) and MFMA loop as R8/R10; smaller LDS
// (14.7KB) -> ~10 blocks/CU for phase interleave.
__global__ __launch_bounds__(128) void k_conv2_mfma(
    const unsigned int* __restrict__ rawp1b, const unsigned short* __restrict__ wb,
    const float* __restrict__ bn1, const float* __restrict__ g2,
    float* __restrict__ c2p, float* __restrict__ part)
{
  __shared__ alignas(16) unsigned int in4[3456];     // 2 imgs, bf16 ch-last [144][12dw]
  __shared__ float sred[2][64], qred[2][64];
  __shared__ alignas(16) float bn1i[48];             // (sc,sh) interleaved, ch 0..23
  __shared__ unsigned short aofft[76];               // A byte-offset per K-chunk
  const int tid = threadIdx.x, blk = blockIdx.x;
  if (tid < 24) {
    const float sc = (tid < 20) ? bn1[tid]      : 0.f;
    const float sh = (tid < 20) ? bn1[20 + tid] : 0.f;
    bn1i[2*tid] = sc; bn1i[2*tid + 1] = sh;
  }
  if (tid >= 32 && tid < 108) {
    const int t = tid - 32;
    const int cc2 = t > 74 ? 74 : t;                 // chunk 75: weights are 0
    const int khw = cc2 / 3, icg = cc2 - khw*3;
    const int kh = khw / 5, kw = khw - kh*5;
    aofft[t] = (unsigned short)((kh*12 + kw)*48 + icg*16);
  }
  __syncthreads();

  // staging: 864 uint4 (2 imgs), unpack bf16 pair -> BN1+ReLU -> repack
  const uint4* src4 = (const uint4*)(rawp1b + (size_t)blk * 3456);
  uint4* dst4 = (uint4*)in4;
  int jj = tid % 3;                                  // uint4 idx mod 3 -> dword chp base jj*4
  for (int k = 0; k < 7; ++k) {
    const int i = k*128 + tid;
    if (i < 864) {
      const uint4 v = src4[i];
      unsigned int o[4];
      #pragma unroll
      for (int m = 0; m < 4; ++m) {
        const float4 ss = *(const float4*)(bn1i + jj*16 + m*4);
        const unsigned int u = (m==0) ? v.x : (m==1) ? v.y : (m==2) ? v.z : v.w;
        const float a = __uint_as_float(u << 16);
        const float b = __uint_as_float(u & 0xffff0000u);
        const float ra = relu_(fmaf(a, ss.x, ss.y));
        const float rb = relu_(fmaf(b, ss.z, ss.w));
        o[m] = pack_bf16x2(ra, rb);
      }
      uint4 ov; ov.x = o[0]; ov.y = o[1]; ov.z = o[2]; ov.w = o[3];
      dst4[i] = ov;
    }
    jj = (jj >= 1) ? jj - 1 : 2;                     // (jj + 128) % 3 == (jj + 2) % 3
  }
  __syncthreads();

  const int wave = tid >> 6, lane = tid & 63;
  const int lo = lane & 15, hi = lane >> 4;
  const char* ibase = (const char*)in4 + wave * 6912;   // 6912 B per image

  const char* bA[4];
  #pragma unroll
  for (int a = 0; a < 4; ++a) {
    const int m = a*16 + lo;
    bA[a] = ibase + ((m >> 3) * 12 + (m & 7)) * 48;
  }
  unsigned short aoffs[19];
  #pragma unroll
  for (int s = 0; s < 19; ++s) aoffs[s] = aofft[s*4 + hi];
  const unsigned short* wbase = wb + hi*512 + lo*8;

  bool gpos[4];
  #pragma unroll
  for (int nf = 0; nf < 4; ++nf) {
    const int n = nf*16 + lo;
    gpos[nf] = (n < 50) ? (g2[n] >= 0.f) : true;
  }

  float4v acc[4][4];
  #pragma unroll
  for (int a = 0; a < 4; ++a)
    #pragma unroll
    for (int nf = 0; nf < 4; ++nf) acc[a][nf] = (float4v){0.f, 0.f, 0.f, 0.f};

  #pragma unroll
  for (int s = 0; s < 19; ++s) {
    short8v av[4], bv[4];
    #pragma unroll
    for (int am = 0; am < 4; ++am)
      av[am] = *(const short8v*)(bA[am] + aoffs[s]);
    const unsigned short* wrow = wbase + s*2048;     // (4s+hi)*512 + lo*8
    #pragma unroll
    for (int nf = 0; nf < 4; ++nf)
      bv[nf] = *(const short8v*)(wrow + nf*128);
    #pragma unroll
    for (int am = 0; am < 4; ++am)
      #pragma unroll
      for (int nf = 0; nf < 4; ++nf)
        acc[am][nf] = __builtin_amdgcn_mfma_f32_16x16x32_bf16(av[am], bv[nf], acc[am][nf], 0, 0, 0);
  }

  const int img = blk*2 + wave;
  #pragma unroll
  for (int nf = 0; nf < 4; ++nf) {
    const int n = nf*16 + lo;
    float sv = 0.f, qv = 0.f;
    #pragma unroll
    for (int am = 0; am < 4; ++am) {
      float4v v = acc[am][nf];
      #pragma unroll
      for (int r = 0; r < 4; ++r) { sv += v[r]; qv += v[r]*v[r]; }
      float h0 = gpos[nf] ? fmaxf(v[0], v[1]) : fminf(v[0], v[1]);
      float h1 = gpos[nf] ? fmaxf(v[2], v[3]) : fminf(v[2], v[3]);
      const float o0 = __shfl_xor(h0, 32);
      const float o1 = __shfl_xor(h1, 32);
      h0 = gpos[nf] ? fmaxf(h0, o0) : fminf(h0, o0);
      h1 = gpos[nf] ? fmaxf(h1, o1) : fminf(h1, o1);
      if (hi < 2 && n < 50) {
        float2 o; o.x = h0; o.y = h1;
        *(float2*)(c2p + (size_t)img*800 + n*16 + am*4 + hi*2) = o;
      }
    }
    sv += __shfl_down(sv, 32); qv += __shfl_down(qv, 32);
    sv += __shfl_down(sv, 16); qv += __shfl_down(qv, 16);
    if (hi == 0) { sred[wave][nf*16 + lo] = sv; qred[wave][nf*16 + lo] = qv; }
  }
  __syncthreads();
  if (tid < 100) {
    const int ch = tid < 50 ? tid : tid - 50;
    if (tid < 50) {
      part[(size_t)ch*4096 + blk]        = sred[0][ch] + sred[1][ch];   // [100][4096]
    } else {
      part[(size_t)(50 + ch)*4096 + blk] = qred[0][ch] + qred[1][ch];
    }
  }
}

// ---- BN finalize (bn1/bn2): transposed partials [2*nch][nblk], coalesced ----
__global__ __launch_bounds__(256) void k_bn_fin(
    const float* __restrict__ part, int nblk, int nch, float N,
    const float* __restrict__ g, const float* __restrict__ b,
    float* __restrict__ out)
{
  __shared__ double rd[4][2];
  const int tid = threadIdx.x, ch = blockIdx.x;
  const int lane = tid & 63, wid = tid >> 6;
  const float* ps = part + (size_t)ch * nblk;
  const float* pq = part + (size_t)(nch + ch) * nblk;
  double s = 0.0, q = 0.0;
  for (int i = tid; i < nblk; i += 256) {
    s += (double)ps[i];
    q += (double)pq[i];
  }
  #pragma unroll
  for (int off = 32; off > 0; off >>= 1) { s += __shfl_down(s, off); q += __shfl_down(q, off); }
  if (lane == 0) { rd[wid][0] = s; rd[wid][1] = q; }
  __syncthreads();
  if (tid == 0) {
    double S = rd[0][0] + rd[1][0] + rd[2][0] + rd[3][0];
    double Q = rd[0][1] + rd[1][1] + rd[2][1] + rd[3][1];
    double mean = S / (double)N;
    double var  = Q / (double)N - mean * mean;
    if (var < 0.0) var = 0.0;
    float scv = (float)((double)g[ch] / sqrt(var + 1e-5));
    out[ch]       = scv;
    out[nch + ch] = b[ch] - (float)mean * scv;
  }
}

// ---- fc1 fused BN2+ReLU: 32 samples/block, 8-lane K-split ----
__global__ __launch_bounds__(256) void k_fc1(
    const float* __restrict__ c2p, const float* __restrict__ bn2,
    const float* __restrict__ fw, float* __restrict__ h_raw,
    float* __restrict__ part)
{
  __shared__ alignas(16) float wl[8000];
  __shared__ float s2[50], h2[50];
  __shared__ float red[4][20];
  const int tid = threadIdx.x;
  for (int i = tid; i < 2000; i += 256)
    ((float4*)wl)[i] = ((const float4*)fw)[i];
  if (tid < 50) { s2[tid] = bn2[tid]; h2[tid] = bn2[50 + tid]; }
  __syncthreads();
  const int s = tid >> 3, kc = tid & 7;
  const int sample = blockIdx.x * 32 + s;
  const float* xr = c2p + (size_t)sample * 800 + kc * 100;
  float acc[10];
  #pragma unroll
  for (int f = 0; f < 10; ++f) acc[f] = 0.f;
  #pragma unroll 5
  for (int c = 0; c < 25; ++c) {
    const int k = kc*100 + c*4;
    float4 v = *(const float4*)(xr + c*4);
    const int oc = k >> 4;
    const float sc = s2[oc], sh = h2[oc];
    v.x = relu_(v.x*sc + sh); v.y = relu_(v.y*sc + sh);
    v.z = relu_(v.z*sc + sh); v.w = relu_(v.w*sc + sh);
    #pragma unroll
    for (int f = 0; f < 10; ++f) {
      const float4 wv = *(const float4*)(wl + f*800 + k);
      acc[f] += v.x*wv.x + v.y*wv.y + v.z*wv.z + v.w*wv.w;
    }
  }
  const int lane = tid & 63, wid = tid >> 6;
  #pragma unroll
  for (int f = 0; f < 10; ++f) {
    acc[f] += __shfl_down(acc[f], 4);
    acc[f] += __shfl_down(acc[f], 2);
    acc[f] += __shfl_down(acc[f], 1);
    float a2 = (kc == 0) ? acc[f] : 0.f;
    float q2 = (kc == 0) ? acc[f]*acc[f] : 0.f;
    if (kc == 0) h_raw[(size_t)sample*10 + f] = acc[f];
    a2 += __shfl_down(a2, 32); q2 += __shfl_down(q2, 32);
    a2 += __shfl_down(a2, 16); q2 += __shfl_down(q2, 16);
    a2 += __shfl_down(a2, 8);  q2 += __shfl_down(q2, 8);
    if (lane == 0) { red[wid][f] = a2; red[wid][10+f] = q2; }
  }
  __syncthreads();
  if (tid < 20) {
    float t = 0.f;
    #pragma unroll
    for (int w2 = 0; w2 < 4; ++w2) t += red[w2][tid];
    part[(size_t)blockIdx.x*20 + tid] = t;
  }
}

// ---- fused: BN3 finalize (redundant per-block) + BN3+ReLU + theta logits
//      -> sigmoid -> tree walk -> mu  AND  per-block S partial (32 samples) ----
__global__ __launch_bounds__(256) void k_theta_mu(
    const float* __restrict__ h_raw, const float* __restrict__ part3,
    const float* __restrict__ g3, const float* __restrict__ be3,
    const float* __restrict__ tw, const float* __restrict__ tb,
    const int* __restrict__ y, float* __restrict__ mu,
    float* __restrict__ spart)
{
  __shared__ float twt[10][256];
  __shared__ float tbl[256];
  __shared__ float hl[32][10];
  __shared__ float pl[32][256];
  __shared__ float red3[4][20];
  __shared__ float bn3s[20];
  __shared__ int   ycls[32];
  const int tid = threadIdx.x, blk = blockIdx.x;
  const int lane = tid & 63, wid = tid >> 6;

  for (int i = tid; i < 2550; i += 256) {
    const int node = i / 10, f = i - node*10;
    twt[f][node] = tw[i];
  }
  if (tid < 10) twt[tid][255] = 0.f;
  tbl[tid] = (tid < 255) ? tb[tid] : 0.f;
  if (tid < 32) ycls[tid] = y[blk*32 + tid];

  float p3[20];
  {
    const float* pr = part3 + (size_t)tid * 20;
    #pragma unroll
    for (int j = 0; j < 20; ++j) p3[j] = pr[j];
    #pragma unroll
    for (int off = 32; off > 0; off >>= 1) {
      #pragma unroll
      for (int j = 0; j < 20; ++j) p3[j] += __shfl_down(p3[j], off);
    }
    if (lane == 0) {
      #pragma unroll
      for (int j = 0; j < 20; ++j) red3[wid][j] = p3[j];
    }
  }
  __syncthreads();
  if (tid < 10) {
    double S = 0.0, Q = 0.0;
    #pragma unroll
    for (int w2 = 0; w2 < 4; ++w2) { S += red3[w2][tid]; Q += red3[w2][10+tid]; }
    double mean = S / 8192.0;
    double var  = Q / 8192.0 - mean*mean;
    if (var < 0.0) var = 0.0;
    float scv = (float)((double)g3[tid] / sqrt(var + 1e-5));
    bn3s[tid]      = scv;
    bn3s[10 + tid] = be3[tid] - (float)mean * scv;
  }
  __syncthreads();

  for (int i = tid; i < 320; i += 256) {
    const int ss = i / 10, f = i - ss*10;
    hl[ss][f] = relu_(h_raw[(size_t)blk*320 + i] * bn3s[f] + bn3s[10 + f]);
  }
  __syncthreads();

  const int node = tid;
  for (int i2 = 0; i2 < 32; ++i2) {
    float h[10];
    #pragma unroll
    for (int f = 0; f < 10; ++f) h[f] = hl[i2][f];
    float d = tbl[node];
    #pragma unroll
    for (int f = 0; f < 10; ++f) d += h[f] * twt[f][node];
    pl[i2][node] = (node < 255) ? 1.f / (1.f + __expf(-d)) : 0.f;
  }
  __syncthreads();

  float sacc[10];
  #pragma unroll
  for (int c = 0; c < 10; ++c) sacc[c] = 0.f;
  for (int i2 = 0; i2 < 32; ++i2) {
    float m = 1.f; int idx = 0;
    #pragma unroll
    for (int k = 0; k < 8; ++k) {
      const int dir = (tid >> (7 - k)) & 1;
      const float pv = pl[i2][idx];
      m *= dir ? pv : (1.f - pv);
      idx += dir ? (1 << (7 - k)) : 1;
    }
    mu[(size_t)(blk*32 + i2)*256 + tid] = m;
    const int c = ycls[i2];
    #pragma unroll
    for (int cc = 0; cc < 10; ++cc) sacc[cc] += (c == cc) ? m : 0.f;
  }
  float* dst = spart + (size_t)blk*2560 + tid*10;
  #pragma unroll
  for (int cc = 0; cc < 10; ++cc) dst[cc] = sacc[cc];
}

// ---- S stage B: reduce 256 partials -> S[2560], 4-way unrolled ----
__global__ __launch_bounds__(256) void k_S_red(
    const float* __restrict__ spart, float* __restrict__ S)
{
  const int e = blockIdx.x * 256 + threadIdx.x;   // 2560
  float s0 = 0.f, s1 = 0.f, s2 = 0.f, s3 = 0.f;
  for (int k = 0; k < 256; k += 4) {
    s0 += spart[(size_t)(k+0)*2560 + e];
    s1 += spart[(size_t)(k+1)*2560 + e];
    s2 += spart[(size_t)(k+2)*2560 + e];
    s3 += spart[(size_t)(k+3)*2560 + e];
  }
  S[e] = (s0 + s1) + (s2 + s3);
}

// ---- fused: pi EM update (redundant per-block, deterministic) + out = log(mu @ pi_new) ----
__global__ __launch_bounds__(256) void k_out(
    const float* __restrict__ mu, const float* __restrict__ pi,
    const float* __restrict__ S, float* __restrict__ out)
{
  __shared__ float plt[10][260];                // pi_new transposed, pad 260
  __shared__ float wred[4][10];
  const int tid = threadIdx.x;
  const int lane = tid & 63, wid = tid >> 6;

  float row[10]; float rs = 0.f;
  #pragma unroll
  for (int c = 0; c < 10; ++c) { row[c] = pi[tid*10 + c]; rs += row[c]; }
  #pragma unroll
  for (int c = 0; c < 10; ++c) row[c] /= rs;
  float pp[10];
  #pragma unroll
  for (int c = 0; c < 10; ++c) pp[c] = row[c];
  #pragma unroll
  for (int off = 32; off > 0; off >>= 1) {
    #pragma unroll
    for (int c = 0; c < 10; ++c) pp[c] += __shfl_down(pp[c], off);
  }
  if (lane == 0) {
    #pragma unroll
    for (int c = 0; c < 10; ++c) wred[wid][c] = pp[c];
  }
  __syncthreads();
  float hs = 0.f; float ph[10];
  #pragma unroll
  for (int c = 0; c < 10; ++c) {
    const float Pp = (wred[0][c] + wred[1][c] + wred[2][c] + wred[3][c]) * (1.f/256.f);
    const float Sv = S[tid*10 + c] / Pp;
    ph[c] = row[c] * Sv;
    hs += ph[c];
  }
  const float ih = 1.f / hs;
  #pragma unroll
  for (int c = 0; c < 10; ++c) plt[c][tid] = ph[c] * ih;
  __syncthreads();

  const int gid = blockIdx.x * 256 + tid;       // 81920 total
  const int b = gid / 10, c = gid % 10;
  const float4* mr4 = (const float4*)(mu + (size_t)b * 256);
  const float*  pc  = &plt[c][0];
  float a0 = 0.f, a1 = 0.f;
  #pragma unroll 4
  for (int l4 = 0; l4 < 64; ++l4) {
    const float4 m = mr4[l4];
    const float4 p = *(const float4*)(pc + 4*l4);
    a0 += m.x*p.x + m.y*p.y;
    a1 += m.z*p.z + m.w*p.w;
  }
  out[gid] = logf(a0 + a1);
}

extern "C" void kernel_launch(void* const* d_in, const int* in_sizes, int n_in,
                              void* d_out, int out_size, void* d_ws, size_t ws_size,
                              hipStream_t stream)
{
  const float* x   = (const float*)d_in[0];
  const int*   y   = (const int*)  d_in[1];
  const float* c1w = (const float*)d_in[2];
  const float* c2w = (const float*)d_in[4];
  const float* g1  = (const float*)d_in[6];
  const float* be1 = (const float*)d_in[7];
  const float* g2  = (const float*)d_in[8];
  const float* be2 = (const float*)d_in[9];
  const float* fw  = (const float*)d_in[10];
  const float* g3  = (const float*)d_in[12];
  const float* be3 = (const float*)d_in[13];
  const float* thw = (const float*)d_in[14];
  const float* thb = (const float*)d_in[15];
  const float* pi  = (const float*)d_in[16];
  float* ws  = (float*)d_ws;
  float* out = (float*)d_out;

  unsigned int*   rawp1b = (unsigned int*)(ws + F_RAWP1B);
  float*          c2p    = ws + F_C2P;
  float*          part1  = ws + F_PART1;
  float*          part2  = ws + F_PART2;
  float*          part3  = ws + F_PART3;
  float*          bn1    = ws + F_BN1;
  float*          bn2    = ws + F_BN2;
  float*          sraw   = ws + F_SRAW;
  unsigned short* wb2    = (unsigned short*)(ws + F_WB2);
  unsigned short* wb1    = (unsigned short*)(ws + F_WB1);
  float*          spart  = ws + F_SPART;
  float*          hraw   = ws + F_HRAW;   // overlays rawp1b (dead after conv2)
  float*          muB    = ws + F_MU;

  k_wprep<<<156, 256, 0, stream>>>(c1w, c2w, wb1, wb2);
  k_conv1_mfma<<<2048, 256, 0, stream>>>(x, wb1, g1, rawp1b, part1);
  k_bn_fin<<<20, 256, 0, stream>>>(part1, 2048, 20, 8192.f * 576.f, g1, be1, bn1);
  k_conv2_mfma<<<4096, 128, 0, stream>>>(rawp1b, wb2, bn1, g2, c2p, part2);
  k_bn_fin<<<50, 256, 0, stream>>>(part2, 4096, 50, 8192.f * 64.f, g2, be2, bn2);
  k_fc1<<<256, 256, 0, stream>>>(c2p, bn2, fw, hraw, part3);
  k_theta_mu<<<256, 256, 0, stream>>>(hraw, part3, g3, be3, thw, thb, y, muB, spart);
  k_S_red<<<10, 256, 0, stream>>>(spart, sraw);
  k_out<<<320, 256, 0, stream>>>(muB, pi, sraw, out);
}

// Round 17
// 162.385 us; speedup vs baseline: 1.0834x; 1.0834x over previous
//
#include <hip/hip_runtime.h>
#include <hip/hip_bf16.h>
#include <math.h>

typedef __attribute__((ext_vector_type(8))) short short8v;
typedef __attribute__((ext_vector_type(4))) float float4v;

// ---------------- workspace layout (dword offsets) ----------------
static const size_t F_RAWP1B = 0;              // bf16 ch-last pooled raw conv1 [8192][144][12dw] = 14,155,776
static const size_t F_C2P    = 14155776;       // fp32 pooled raw conv2 [8192][800] = 6,553,600
static const size_t F_PART1  = 20709376;       // 2048*40
static const size_t F_PART2  = 21037056;       // 2048*100
static const size_t F_PART3  = 21241856;       // 256*20
static const size_t F_BN1    = 21246976;       // 40
static const size_t F_BN2    = 21247016;       // 100
static const size_t F_SRAW   = 21247136;       // 2560
static const size_t F_WB2    = 21252256;       // 19456 (76*64*8 bf16)
static const size_t F_WB1    = 21271712;       // 512   (32*32 bf16)
static const size_t F_SPART  = 21272224;       // 256*2560 = 655,360
// overlays in rawp1b region (dead after conv2):
static const size_t F_HRAW   = 0;              // 8192*10
static const size_t F_MU     = 81920;          // 8192*256

__device__ __forceinline__ float relu_(float v) { return v > 0.f ? v : 0.f; }

__device__ __forceinline__ unsigned int pack_bf16x2(float a, float b) {
  __hip_bfloat16 ha = __float2bfloat16(a), hb = __float2bfloat16(b);
  unsigned short ua, ub;
  __builtin_memcpy(&ua, &ha, 2); __builtin_memcpy(&ub, &hb, 2);
  return ((unsigned int)ub << 16) | ua;
}

__device__ __forceinline__ unsigned short cvt_bf16(float a) {
  __hip_bfloat16 h = __float2bfloat16(a);
  unsigned short u; __builtin_memcpy(&u, &h, 2);
  return u;
}

__device__ __forceinline__ float pick_(float a, float b, bool mx) {
  return mx ? fmaxf(a, b) : fminf(a, b);
}

// ---- merged weight prep: wb1[n(32)][k(32)] (k=kh*6+kw) + wb2[cc(76)][n(64)][j(8)] ----
__global__ __launch_bounds__(256) void k_wprep(
    const float* __restrict__ w1, const float* __restrict__ w2,
    unsigned short* __restrict__ wb1, unsigned short* __restrict__ wb2)
{
  const int gi = blockIdx.x * 256 + threadIdx.x;     // 39936 total
  if (gi < 1024) {
    const int n = gi >> 5, k = gi & 31;
    const int kh = k / 6, kw = k - kh*6;
    float v = (n < 20 && kh < 5 && kw < 5) ? w1[n*25 + kh*5 + kw] : 0.f;
    wb1[gi] = cvt_bf16(v);
  } else {
    const int idx = gi - 1024;                       // 38912
    const int cc = idx >> 9;
    const int rem = idx & 511;
    const int n = rem >> 3, j = rem & 7;
    float v = 0.f;
    if (cc < 75 && n < 50) {
      const int khw = cc / 3, icg = cc - khw*3;
      const int ic = icg*8 + j;
      if (ic < 20) {
        const int kh = khw / 5, kw = khw - kh*5;
        v = w2[((n*20 + ic)*5 + kh)*5 + kw];
      }
    }
    wb2[idx] = cvt_bf16(v);
  }
}

// ---- conv1 MFMA implicit GEMM, 4 imgs/block, double-buffered pipelined ----
// v3 (R15-measured): tile loop split into 3 groups of 3 (non-unrolled) so only
// acc[3][2] is live -> VGPR 48, occupancy 36%. Stats: per-t3 accumulators.
__global__ __launch_bounds__(256) void k_conv1_mfma(
    const float* __restrict__ x, const unsigned short* __restrict__ wb1,
    const float* __restrict__ g1, unsigned int* __restrict__ rawp1b,
    float* __restrict__ part)
{
  __shared__ alignas(16) unsigned short xpk[2][1568];   // [buf][2 copies][28][28]
  __shared__ float sred[4][32], qred[4][32];
  const int tid = threadIdx.x, blk = blockIdx.x;
  const int img0 = blk * 4;
  const int wave = tid >> 6, lane = tid & 63, lo = lane & 15, hi = lane >> 4;

  // ---- hoisted per-block setup ----
  const short8v bfr0 = *(const short8v*)(wb1 + (lo*32 + hi*8));
  const short8v bfr1 = *(const short8v*)(wb1 + ((16+lo)*32 + hi*8));
  const unsigned enc = (hi==0) ? 0x0E020100u
                     : (hi==1) ? 0x1D1C100Fu
                     : (hi==2) ? 0x2C2B2A1Eu
                     :           0x003A3938u;   // hi=3: jj3 = zero-weight dummy
  const int off0 = enc & 255, off1 = (enc>>8)&255, off2 = (enc>>16)&255, off3 = enc>>24;
  const int pb   = (lo & 1) * 392;              // parity copy, dwords
  const int oyp  = (lo >> 1) & 1, qoff = lo >> 2;
  const int inv  = pb + (6*wave + oyp)*14;
  const bool gp0 = (g1[lo] >= 0.f);
  const bool gp1 = (lo < 4) ? (g1[16+lo] >= 0.f) : true;
  // staging geometry: 224 active threads, 8-per-row (7 quads + 1 idle)
  const int sr = tid >> 3, sq = tid & 7;
  const bool act = (tid < 224) && (sq < 7);
  const int su0 = sr*7 + sq;                    // uint2 index, copy0
  const int su1 = 196 + su0;                    // uint2 index, copy1

  float4 sv = make_float4(0.f, 0.f, 0.f, 0.f);
  // prologue: stage image 0
  if (act) sv = *(const float4*)(x + (size_t)img0 * 784 + sr*28 + 4*sq);
  {
    float n0 = __shfl_down(sv.x, 1);
    n0 = (sq == 6) ? 0.f : n0;
    if (act) {
      uint2* xb2 = (uint2*)&xpk[0][0];
      uint2 t0; t0.x = pack_bf16x2(sv.x, sv.y); t0.y = pack_bf16x2(sv.z, sv.w);
      uint2 t1; t1.x = pack_bf16x2(sv.y, sv.z); t1.y = pack_bf16x2(sv.w, n0);
      xb2[su0] = t0;
      xb2[su1] = t1;
    }
  }
  __syncthreads();

  // block-level stats, per-t3 accumulators (static indexing)
  float bs0[3] = {0.f, 0.f, 0.f}, bq0[3] = {0.f, 0.f, 0.f};
  float bs1[3] = {0.f, 0.f, 0.f}, bq1[3] = {0.f, 0.f, 0.f};
  int cur = 0;
  for (int ii = 0; ii < 4; ++ii) {
    // issue next image's global load early (latency hides under compute)
    if (ii < 3 && act)
      sv = *(const float4*)(x + (size_t)(img0 + ii + 1) * 784 + sr*28 + 4*sq);
    const unsigned int* xpd = (const unsigned int*)&xpk[cur][0];
    unsigned int* dst = rawp1b + (size_t)(img0 + ii) * 1728;

    #pragma unroll 1
    for (int g = 0; g < 3; ++g) {
      float4v acc[3][2];
      #pragma unroll
      for (int t3 = 0; t3 < 3; ++t3) {
        acc[t3][0] = (float4v){0.f,0.f,0.f,0.f};
        acc[t3][1] = (float4v){0.f,0.f,0.f,0.f};
      }
      #pragma unroll
      for (int t3 = 0; t3 < 3; ++t3) {
        const int base = inv + g*28 + t3*4 + qoff;
        union { unsigned int u[4]; short8v v; } cu;
        cu.u[0] = xpd[base + off0];
        cu.u[1] = xpd[base + off1];
        cu.u[2] = xpd[base + off2];
        cu.u[3] = xpd[base + off3];
        acc[t3][0] = __builtin_amdgcn_mfma_f32_16x16x32_bf16(cu.v, bfr0, acc[t3][0], 0, 0, 0);
        acc[t3][1] = __builtin_amdgcn_mfma_f32_16x16x32_bf16(cu.v, bfr1, acc[t3][1], 0, 0, 0);
      }
      #pragma unroll
      for (int t3 = 0; t3 < 3; ++t3) {
        const int T = wave*9 + g*3 + t3;
        const int q = T*4 + hi;
        const float4v v0 = acc[t3][0];
        const float4v v1 = acc[t3][1];
        #pragma unroll
        for (int r = 0; r < 4; ++r) { bs0[t3] += v0[r]; bq0[t3] += v0[r]*v0[r]; }
        #pragma unroll
        for (int r = 0; r < 4; ++r) { bs1[t3] += v1[r]; bq1[t3] += v1[r]*v1[r]; }
        const float p0 = pick_(pick_(v0[0], v0[1], gp0), pick_(v0[2], v0[3], gp0), gp0);
        const float p1 = pick_(pick_(v1[0], v1[1], gp1), pick_(v1[2], v1[3], gp1), gp1);
        const float o0 = __shfl_down(p0, 1);
        const float o1 = __shfl_down(p1, 1);
        if ((lo & 1) == 0) {
          dst[q*12 + (lo >> 1)] = pack_bf16x2(p0, o0);          // oc pair (lo, lo+1)
          if (lo < 8)
            dst[q*12 + 8 + (lo >> 1)] = pack_bf16x2(p1, o1);    // oc 16.. (pads=0)
        }
      }
    }

    // write next image into the other buffer (disjoint from xpk[cur])
    if (ii < 3) {
      float n0 = __shfl_down(sv.x, 1);
      n0 = (sq == 6) ? 0.f : n0;
      if (act) {
        uint2* xb2 = (uint2*)&xpk[cur ^ 1][0];
        uint2 t0; t0.x = pack_bf16x2(sv.x, sv.y); t0.y = pack_bf16x2(sv.z, sv.w);
        uint2 t1; t1.x = pack_bf16x2(sv.y, sv.z); t1.y = pack_bf16x2(sv.w, n0);
        xb2[su0] = t0;
        xb2[su1] = t1;
      }
    }
    __syncthreads();
    cur ^= 1;
  }

  // ---- single block-level stats reduction ----
  float bsv0 = bs0[0] + bs0[1] + bs0[2], bqv0 = bq0[0] + bq0[1] + bq0[2];
  float bsv1 = bs1[0] + bs1[1] + bs1[2], bqv1 = bq1[0] + bq1[1] + bq1[2];
  bsv0 += __shfl_down(bsv0, 32); bqv0 += __shfl_down(bqv0, 32);
  bsv0 += __shfl_down(bsv0, 16); bqv0 += __shfl_down(bqv0, 16);
  bsv1 += __shfl_down(bsv1, 32); bqv1 += __shfl_down(bqv1, 32);
  bsv1 += __shfl_down(bsv1, 16); bqv1 += __shfl_down(bqv1, 16);
  if (hi == 0) {
    sred[wave][lo] = bsv0; sred[wave][16+lo] = bsv1;
    qred[wave][lo] = bqv0; qred[wave][16+lo] = bqv1;
  }
  __syncthreads();
  if (tid < 20) {
    float s = 0.f, q = 0.f;
    #pragma unroll
    for (int w2 = 0; w2 < 4; ++w2) { s += sred[w2][tid]; q += qred[w2][tid]; }
    part[(size_t)blk*40 + tid]      = s;
    part[(size_t)blk*40 + 20 + tid] = q;
  }
}

// ---- conv2 implicit-GEMM MFMA (R8/R10/R15-measured form) ----
__global__ __launch_bounds__(256) void k_conv2_mfma(
    const unsigned int* __restrict__ rawp1b, const unsigned short* __restrict__ wb,
    const float* __restrict__ bn1, const float* __restrict__ g2,
    float* __restrict__ c2p, float* __restrict__ part)
{
  __shared__ alignas(16) unsigned int in4[6912];     // 4 imgs, bf16 ch-last [144][12dw]
  __shared__ float sred[4][64], qred[4][64];
  __shared__ alignas(16) float bn1i[48];             // (sc,sh) interleaved, ch 0..23
  __shared__ unsigned short aofft[76];               // A byte-offset per K-chunk
  const int tid = threadIdx.x, blk = blockIdx.x;
  if (tid < 24) {
    const float sc = (tid < 20) ? bn1[tid]      : 0.f;
    const float sh = (tid < 20) ? bn1[20 + tid] : 0.f;
    bn1i[2*tid] = sc; bn1i[2*tid + 1] = sh;
  }
  if (tid < 76) {
    const int cc2 = tid > 74 ? 74 : tid;             // chunk 75: weights are 0
    const int khw = cc2 / 3, icg = cc2 - khw*3;
    const int kh = khw / 5, kw = khw - kh*5;
    aofft[tid] = (unsigned short)((kh*12 + kw)*48 + icg*16);
  }
  __syncthreads();

  const uint4* src4 = (const uint4*)(rawp1b + (size_t)blk * 6912);
  uint4* dst4 = (uint4*)in4;
  int jj = tid % 3;                                  // dword chp base = jj*4
  for (int k = 0; k < 7; ++k) {
    const int i = k*256 + tid;
    if (i < 1728) {
      const uint4 v = src4[i];
      unsigned int o[4];
      #pragma unroll
      for (int m = 0; m < 4; ++m) {
        const float4 ss = *(const float4*)(bn1i + jj*16 + m*4);
        const unsigned int u = (m==0) ? v.x : (m==1) ? v.y : (m==2) ? v.z : v.w;
        const float a = __uint_as_float(u << 16);
        const float b = __uint_as_float(u & 0xffff0000u);
        const float ra = relu_(fmaf(a, ss.x, ss.y));
        const float rb = relu_(fmaf(b, ss.z, ss.w));
        o[m] = pack_bf16x2(ra, rb);
      }
      uint4 ov; ov.x = o[0]; ov.y = o[1]; ov.z = o[2]; ov.w = o[3];
      dst4[i] = ov;
    }
    jj = (jj == 2) ? 0 : jj + 1;                     // 256 % 3 == 1
  }
  __syncthreads();

  const int wave = tid >> 6, lane = tid & 63;
  const int lo = lane & 15, hi = lane >> 4;
  const char* ibase = (const char*)in4 + wave * 6912;

  const char* bA[4];
  #pragma unroll
  for (int a = 0; a < 4; ++a) {
    const int m = a*16 + lo;
    bA[a] = ibase + ((m >> 3) * 12 + (m & 7)) * 48;
  }
  unsigned short aoffs[19];
  #pragma unroll
  for (int s = 0; s < 19; ++s) aoffs[s] = aofft[s*4 + hi];
  const unsigned short* wbase = wb + hi*512 + lo*8;

  bool gpos[4];
  #pragma unroll
  for (int nf = 0; nf < 4; ++nf) {
    const int n = nf*16 + lo;
    gpos[nf] = (n < 50) ? (g2[n] >= 0.f) : true;
  }

  float4v acc[4][4];
  #pragma unroll
  for (int a = 0; a < 4; ++a)
    #pragma unroll
    for (int nf = 0; nf < 4; ++nf) acc[a][nf] = (float4v){0.f, 0.f, 0.f, 0.f};

  #pragma unroll
  for (int s = 0; s < 19; ++s) {
    short8v av[4], bv[4];
    #pragma unroll
    for (int am = 0; am < 4; ++am)
      av[am] = *(const short8v*)(bA[am] + aoffs[s]);
    const unsigned short* wrow = wbase + s*2048;     // (4s+hi)*512 + lo*8
    #pragma unroll
    for (int nf = 0; nf < 4; ++nf)
      bv[nf] = *(const short8v*)(wrow + nf*128);
    #pragma unroll
    for (int am = 0; am < 4; ++am)
      #pragma unroll
      for (int nf = 0; nf < 4; ++nf)
        acc[am][nf] = __builtin_amdgcn_mfma_f32_16x16x32_bf16(av[am], bv[nf], acc[am][nf], 0, 0, 0);
  }

  const int img = blk*4 + wave;
  #pragma unroll
  for (int nf = 0; nf < 4; ++nf) {
    const int n = nf*16 + lo;
    float sv = 0.f, qv = 0.f;
    #pragma unroll
    for (int am = 0; am < 4; ++am) {
      float4v v = acc[am][nf];
      #pragma unroll
      for (int r = 0; r < 4; ++r) { sv += v[r]; qv += v[r]*v[r]; }
      float h0 = gpos[nf] ? fmaxf(v[0], v[1]) : fminf(v[0], v[1]);
      float h1 = gpos[nf] ? fmaxf(v[2], v[3]) : fminf(v[2], v[3]);
      const float o0 = __shfl_xor(h0, 32);
      const float o1 = __shfl_xor(h1, 32);
      h0 = gpos[nf] ? fmaxf(h0, o0) : fminf(h0, o0);
      h1 = gpos[nf] ? fmaxf(h1, o1) : fminf(h1, o1);
      if (hi < 2 && n < 50) {
        float2 o; o.x = h0; o.y = h1;
        *(float2*)(c2p + (size_t)img*800 + n*16 + am*4 + hi*2) = o;
      }
    }
    sv += __shfl_down(sv, 32); qv += __shfl_down(qv, 32);
    sv += __shfl_down(sv, 16); qv += __shfl_down(qv, 16);
    if (hi == 0) { sred[wave][nf*16 + lo] = sv; qred[wave][nf*16 + lo] = qv; }
  }
  __syncthreads();
  if (tid < 100) {
    const int ch = tid < 50 ? tid : tid - 50;
    float t = 0.f;
    if (tid < 50) {
      #pragma unroll
      for (int w2 = 0; w2 < 4; ++w2) t += sred[w2][ch];
      part[(size_t)blk*100 + ch] = t;
    } else {
      #pragma unroll
      for (int w2 = 0; w2 < 4; ++w2) t += qred[w2][ch];
      part[(size_t)blk*100 + 50 + ch] = t;
    }
  }
}

// ---- BN finalize (bn1/bn2): reduce per-block partials (double) ----
__global__ __launch_bounds__(256) void k_bn_fin(
    const float* __restrict__ part, int nblk, int nch, float N,
    const float* __restrict__ g, const float* __restrict__ b,
    float* __restrict__ out)
{
  __shared__ double rd[4][2];
  const int tid = threadIdx.x, ch = blockIdx.x;
  const int lane = tid & 63, wid = tid >> 6;
  double s = 0.0, q = 0.0;
  for (int i = tid; i < nblk; i += 256) {
    s += (double)part[(size_t)i*2*nch + ch];
    q += (double)part[(size_t)i*2*nch + nch + ch];
  }
  #pragma unroll
  for (int off = 32; off > 0; off >>= 1) { s += __shfl_down(s, off); q += __shfl_down(q, off); }
  if (lane == 0) { rd[wid][0] = s; rd[wid][1] = q; }
  __syncthreads();
  if (tid == 0) {
    double S = rd[0][0] + rd[1][0] + rd[2][0] + rd[3][0];
    double Q = rd[0][1] + rd[1][1] + rd[2][1] + rd[3][1];
    double mean = S / (double)N;
    double var  = Q / (double)N - mean * mean;
    if (var < 0.0) var = 0.0;
    float scv = (float)((double)g[ch] / sqrt(var + 1e-5));
    out[ch]       = scv;
    out[nch + ch] = b[ch] - (float)mean * scv;
  }
}

// ---- fc1 fused BN2+ReLU: 32 samples/block, 8-lane K-split ----
__global__ __launch_bounds__(256) void k_fc1(
    const float* __restrict__ c2p, const float* __restrict__ bn2,
    const float* __restrict__ fw, float* __restrict__ h_raw,
    float* __restrict__ part)
{
  __shared__ alignas(16) float wl[8000];
  __shared__ float s2[50], h2[50];
  __shared__ float red[4][20];
  const int tid = threadIdx.x;
  for (int i = tid; i < 2000; i += 256)
    ((float4*)wl)[i] = ((const float4*)fw)[i];
  if (tid < 50) { s2[tid] = bn2[tid]; h2[tid] = bn2[50 + tid]; }
  __syncthreads();
  const int s = tid >> 3, kc = tid & 7;
  const int sample = blockIdx.x * 32 + s;
  const float* xr = c2p + (size_t)sample * 800 + kc * 100;
  float acc[10];
  #pragma unroll
  for (int f = 0; f < 10; ++f) acc[f] = 0.f;
  #pragma unroll 5
  for (int c = 0; c < 25; ++c) {
    const int k = kc*100 + c*4;
    float4 v = *(const float4*)(xr + c*4);
    const int oc = k >> 4;
    const float sc = s2[oc], sh = h2[oc];
    v.x = relu_(v.x*sc + sh); v.y = relu_(v.y*sc + sh);
    v.z = relu_(v.z*sc + sh); v.w = relu_(v.w*sc + sh);
    #pragma unroll
    for (int f = 0; f < 10; ++f) {
      const float4 wv = *(const float4*)(wl + f*800 + k);
      acc[f] += v.x*wv.x + v.y*wv.y + v.z*wv.z + v.w*wv.w;
    }
  }
  const int lane = tid & 63, wid = tid >> 6;
  #pragma unroll
  for (int f = 0; f < 10; ++f) {
    acc[f] += __shfl_down(acc[f], 4);
    acc[f] += __shfl_down(acc[f], 2);
    acc[f] += __shfl_down(acc[f], 1);
    float a2 = (kc == 0) ? acc[f] : 0.f;
    float q2 = (kc == 0) ? acc[f]*acc[f] : 0.f;
    if (kc == 0) h_raw[(size_t)sample*10 + f] = acc[f];
    a2 += __shfl_down(a2, 32); q2 += __shfl_down(q2, 32);
    a2 += __shfl_down(a2, 16); q2 += __shfl_down(q2, 16);
    a2 += __shfl_down(a2, 8);  q2 += __shfl_down(q2, 8);
    if (lane == 0) { red[wid][f] = a2; red[wid][10+f] = q2; }
  }
  __syncthreads();
  if (tid < 20) {
    float t = 0.f;
    #pragma unroll
    for (int w2 = 0; w2 < 4; ++w2) t += red[w2][tid];
    part[(size_t)blockIdx.x*20 + tid] = t;
  }
}

// ---- fused: BN3 finalize (redundant per-block) + BN3+ReLU + theta logits
//      -> sigmoid -> tree walk -> mu  AND  per-block S partial (32 samples) ----
__global__ __launch_bounds__(256) void k_theta_mu(
    const float* __restrict__ h_raw, const float* __restrict__ part3,
    const float* __restrict__ g3, const float* __restrict__ be3,
    const float* __restrict__ tw, const float* __restrict__ tb,
    const int* __restrict__ y, float* __restrict__ mu,
    float* __restrict__ spart)
{
  __shared__ float twt[10][256];
  __shared__ float tbl[256];
  __shared__ float hl[32][10];
  __shared__ float pl[32][256];
  __shared__ float red3[4][20];
  __shared__ float bn3s[20];
  __shared__ int   ycls[32];
  const int tid = threadIdx.x, blk = blockIdx.x;
  const int lane = tid & 63, wid = tid >> 6;

  for (int i = tid; i < 2550; i += 256) {
    const int node = i / 10, f = i - node*10;
    twt[f][node] = tw[i];
  }
  if (tid < 10) twt[tid][255] = 0.f;
  tbl[tid] = (tid < 255) ? tb[tid] : 0.f;
  if (tid < 32) ycls[tid] = y[blk*32 + tid];

  float p3[20];
  {
    const float* pr = part3 + (size_t)tid * 20;
    #pragma unroll
    for (int j = 0; j < 20; ++j) p3[j] = pr[j];
    #pragma unroll
    for (int off = 32; off > 0; off >>= 1) {
      #pragma unroll
      for (int j = 0; j < 20; ++j) p3[j] += __shfl_down(p3[j], off);
    }
    if (lane == 0) {
      #pragma unroll
      for (int j = 0; j < 20; ++j) red3[wid][j] = p3[j];
    }
  }
  __syncthreads();
  if (tid < 10) {
    double S = 0.0, Q = 0.0;
    #pragma unroll
    for (int w2 = 0; w2 < 4; ++w2) { S += red3[w2][tid]; Q += red3[w2][10+tid]; }
    double mean = S / 8192.0;
    double var  = Q / 8192.0 - mean*mean;
    if (var < 0.0) var = 0.0;
    float scv = (float)((double)g3[tid] / sqrt(var + 1e-5));
    bn3s[tid]      = scv;
    bn3s[10 + tid] = be3[tid] - (float)mean * scv;
  }
  __syncthreads();

  for (int i = tid; i < 320; i += 256) {
    const int ss = i / 10, f = i - ss*10;
    hl[ss][f] = relu_(h_raw[(size_t)blk*320 + i] * bn3s[f] + bn3s[10 + f]);
  }
  __syncthreads();

  const int node = tid;
  for (int i2 = 0; i2 < 32; ++i2) {
    float h[10];
    #pragma unroll
    for (int f = 0; f < 10; ++f) h[f] = hl[i2][f];
    float d = tbl[node];
    #pragma unroll
    for (int f = 0; f < 10; ++f) d += h[f] * twt[f][node];
    pl[i2][node] = (node < 255) ? 1.f / (1.f + __expf(-d)) : 0.f;
  }
  __syncthreads();

  float sacc[10];
  #pragma unroll
  for (int c = 0; c < 10; ++c) sacc[c] = 0.f;
  for (int i2 = 0; i2 < 32; ++i2) {
    float m = 1.f; int idx = 0;
    #pragma unroll
    for (int k = 0; k < 8; ++k) {
      const int dir = (tid >> (7 - k)) & 1;
      const float pv = pl[i2][idx];
      m *= dir ? pv : (1.f - pv);
      idx += dir ? (1 << (7 - k)) : 1;
    }
    mu[(size_t)(blk*32 + i2)*256 + tid] = m;
    const int c = ycls[i2];
    #pragma unroll
    for (int cc = 0; cc < 10; ++cc) sacc[cc] += (c == cc) ? m : 0.f;
  }
  float* dst = spart + (size_t)blk*2560 + tid*10;
  #pragma unroll
  for (int cc = 0; cc < 10; ++cc) dst[cc] = sacc[cc];
}

// ---- S stage B: reduce 256 partials -> S[2560] ----
__global__ __launch_bounds__(256) void k_S_red(
    const float* __restrict__ spart, float* __restrict__ S)
{
  const int e = blockIdx.x * 256 + threadIdx.x;   // 2560
  float s = 0.f;
  for (int k = 0; k < 256; ++k) s += spart[(size_t)k*2560 + e];
  S[e] = s;
}

// ---- fused: pi EM update (redundant per-block, deterministic) + out = log(mu @ pi_new) ----
__global__ __launch_bounds__(256) void k_out(
    const float* __restrict__ mu, const float* __restrict__ pi,
    const float* __restrict__ S, float* __restrict__ out)
{
  __shared__ float plt[10][260];                // pi_new transposed, pad 260
  __shared__ float wred[4][10];
  const int tid = threadIdx.x;
  const int lane = tid & 63, wid = tid >> 6;

  float row[10]; float rs = 0.f;
  #pragma unroll
  for (int c = 0; c < 10; ++c) { row[c] = pi[tid*10 + c]; rs += row[c]; }
  #pragma unroll
  for (int c = 0; c < 10; ++c) row[c] /= rs;
  float pp[10];
  #pragma unroll
  for (int c = 0; c < 10; ++c) pp[c] = row[c];
  #pragma unroll
  for (int off = 32; off > 0; off >>= 1) {
    #pragma unroll
    for (int c = 0; c < 10; ++c) pp[c] += __shfl_down(pp[c], off);
  }
  if (lane == 0) {
    #pragma unroll
    for (int c = 0; c < 10; ++c) wred[wid][c] = pp[c];
  }
  __syncthreads();
  float hs = 0.f; float ph[10];
  #pragma unroll
  for (int c = 0; c < 10; ++c) {
    const float Pp = (wred[0][c] + wred[1][c] + wred[2][c] + wred[3][c]) * (1.f/256.f);
    const float Sv = S[tid*10 + c] / Pp;
    ph[c] = row[c] * Sv;
    hs += ph[c];
  }
  const float ih = 1.f / hs;
  #pragma unroll
  for (int c = 0; c < 10; ++c) plt[c][tid] = ph[c] * ih;
  __syncthreads();

  const int gid = blockIdx.x * 256 + tid;       // 81920 total
  const int b = gid / 10, c = gid % 10;
  const float4* mr4 = (const float4*)(mu + (size_t)b * 256);
  const float*  pc  = &plt[c][0];
  float a0 = 0.f, a1 = 0.f;
  #pragma unroll 4
  for (int l4 = 0; l4 < 64; ++l4) {
    const float4 m = mr4[l4];
    const float4 p = *(const float4*)(pc + 4*l4);
    a0 += m.x*p.x + m.y*p.y;
    a1 += m.z*p.z + m.w*p.w;
  }
  out[gid] = logf(a0 + a1);
}

extern "C" void kernel_launch(void* const* d_in, const int* in_sizes, int n_in,
                              void* d_out, int out_size, void* d_ws, size_t ws_size,
                              hipStream_t stream)
{
  const float* x   = (const float*)d_in[0];
  const int*   y   = (const int*)  d_in[1];
  const float* c1w = (const float*)d_in[2];
  const float* c2w = (const float*)d_in[4];
  const float* g1  = (const float*)d_in[6];
  const float* be1 = (const float*)d_in[7];
  const float* g2  = (const float*)d_in[8];
  const float* be2 = (const float*)d_in[9];
  const float* fw  = (const float*)d_in[10];
  const float* g3  = (const float*)d_in[12];
  const float* be3 = (const float*)d_in[13];
  const float* thw = (const float*)d_in[14];
  const float* thb = (const float*)d_in[15];
  const float* pi  = (const float*)d_in[16];
  float* ws  = (float*)d_ws;
  float* out = (float*)d_out;

  unsigned int*   rawp1b = (unsigned int*)(ws + F_RAWP1B);
  float*          c2p    = ws + F_C2P;
  float*          part1  = ws + F_PART1;
  float*          part2  = ws + F_PART2;
  float*          part3  = ws + F_PART3;
  float*          bn1    = ws + F_BN1;
  float*          bn2    = ws + F_BN2;
  float*          sraw   = ws + F_SRAW;
  unsigned short* wb2    = (unsigned short*)(ws + F_WB2);
  unsigned short* wb1    = (unsigned short*)(ws + F_WB1);
  float*          spart  = ws + F_SPART;
  float*          hraw   = ws + F_HRAW;   // overlays rawp1b (dead after conv2)
  float*          muB    = ws + F_MU;

  k_wprep<<<156, 256, 0, stream>>>(c1w, c2w, wb1, wb2);
  k_conv1_mfma<<<2048, 256, 0, stream>>>(x, wb1, g1, rawp1b, part1);
  k_bn_fin<<<20, 256, 0, stream>>>(part1, 2048, 20, 8192.f * 576.f, g1, be1, bn1);
  k_conv2_mfma<<<2048, 256, 0, stream>>>(rawp1b, wb2, bn1, g2, c2p, part2);
  k_bn_fin<<<50, 256, 0, stream>>>(part2, 2048, 50, 8192.f * 64.f, g2, be2, bn2);
  k_fc1<<<256, 256, 0, stream>>>(c2p, bn2, fw, hraw, part3);
  k_theta_mu<<<256, 256, 0, stream>>>(hraw, part3, g3, be3, thw, thb, y, muB, spart);
  k_S_red<<<10, 256, 0, stream>>>(spart, sraw);
  k_out<<<320, 256, 0, stream>>>(muB, pi, sraw, out);
}